// Round 5
// baseline (587.269 us; speedup 1.0000x reference)
//
#include <hip/hip_runtime.h>
#include <hip/hip_fp16.h>
#include <math.h>

#define D 64
#define RB 1024          // nodes per range (must match >>10 / &1023 below)
#define EB 2048          // edges per partition block
#define NRMAX 128        // static LDS sizing; NR = ceil(N/RB) must be <= NRMAX
#define KHOPS 10
#define SPMM_BLOCKS 2048 // persistent spmm grid: 4 waves/block, grid-stride

// ---- helpers ------------------------------------------------------------

typedef union { uint4 u; __half2 h[4]; } U4H;

// ---- multisplit CSR build (no global atomics anywhere) ------------------

__global__ void countA(const int* __restrict__ dst, int* __restrict__ countsA_T,
                       int E, int NR, int NBLK) {
    __shared__ int hist[NRMAX];
    int t = threadIdx.x;
    for (int i = t; i < NR; i += 256) hist[i] = 0;
    __syncthreads();
    int base = blockIdx.x * EB + t;
    #pragma unroll
    for (int j = 0; j < EB / 256; ++j) {
        int e = base + j * 256;
        if (e < E) atomicAdd(&hist[dst[e] >> 10], 1);
    }
    __syncthreads();
    for (int i = t; i < NR; i += 256) countsA_T[i * NBLK + blockIdx.x] = hist[i];
}

__global__ void block_sums(const int* __restrict__ arr, int* __restrict__ bsum, int n) {
    int base = blockIdx.x * 1024;
    int t = threadIdx.x;
    int v = 0;
    #pragma unroll
    for (int j = 0; j < 4; ++j) {
        int i = base + t + j * 256;
        if (i < n) v += arr[i];
    }
    #pragma unroll
    for (int m = 32; m >= 1; m >>= 1) v += __shfl_xor(v, m, 64);
    __shared__ int ws[4];
    if ((t & 63) == 0) ws[t >> 6] = v;
    __syncthreads();
    if (t == 0) bsum[blockIdx.x] = ws[0] + ws[1] + ws[2] + ws[3];
}

__global__ void scan_bsums(int* __restrict__ bsum, int nb) {
    __shared__ int tmp[1024];
    int t = threadIdx.x;
    int v = (t < nb) ? bsum[t] : 0;
    tmp[t] = v;
    __syncthreads();
    for (int off = 1; off < 1024; off <<= 1) {
        int x = (t >= off) ? tmp[t - off] : 0;
        __syncthreads();
        tmp[t] += x;
        __syncthreads();
    }
    if (t < nb) bsum[t] = tmp[t] - v;
}

__global__ void gen_scan2(const int* __restrict__ arr, const int* __restrict__ bsum,
                          int* __restrict__ out, int n) {
    __shared__ int tmp[1024];
    int base = blockIdx.x * 1024;
    int t = threadIdx.x;
    int i = base + t;
    int v = (i < n) ? arr[i] : 0;
    tmp[t] = v;
    __syncthreads();
    for (int off = 1; off < 1024; off <<= 1) {
        int x = (t >= off) ? tmp[t - off] : 0;
        __syncthreads();
        tmp[t] += x;
        __syncthreads();
    }
    if (i < n) out[i] = bsum[blockIdx.x] + tmp[t] - v;
}

__global__ void passA2(const int* __restrict__ src, const int* __restrict__ dst,
                       const int* __restrict__ baseA, unsigned int* __restrict__ ebuf2,
                       int E, int NR, int NBLK) {
    __shared__ int cur[NRMAX];
    int t = threadIdx.x;
    for (int i = t; i < NR; i += 256) cur[i] = baseA[i * NBLK + blockIdx.x];
    __syncthreads();
    int base = blockIdx.x * EB + t;
    #pragma unroll
    for (int j = 0; j < EB / 256; ++j) {
        int e = base + j * 256;
        if (e < E) {
            int v = dst[e];
            int pos = atomicAdd(&cur[v >> 10], 1);
            ebuf2[pos] = (unsigned int)src[e] | ((unsigned int)(v & (RB - 1)) << 17);
        }
    }
}

__global__ void range_build(const unsigned int* __restrict__ ebuf2,
                            const int* __restrict__ baseA,
                            int* __restrict__ offsets, float* __restrict__ norm,
                            int* __restrict__ csr, int N, int E, int NR, int NBLK) {
    __shared__ int cnt[RB];
    __shared__ int sc[RB];
    int rg = blockIdx.x;
    int t = threadIdx.x;
    int r0 = baseA[rg * NBLK];
    int r1 = (rg + 1 < NR) ? baseA[(rg + 1) * NBLK] : E;
    cnt[t] = 0;
    __syncthreads();
    for (int i = r0 + t; i < r1; i += RB)
        atomicAdd(&cnt[ebuf2[i] >> 17], 1);
    __syncthreads();
    int v = cnt[t];
    sc[t] = v;
    __syncthreads();
    for (int off = 1; off < RB; off <<= 1) {
        int x = (t >= off) ? sc[t - off] : 0;
        __syncthreads();
        sc[t] += x;
        __syncthreads();
    }
    int excl = sc[t] - v;
    int node = rg * RB + t;
    if (node < N) {
        offsets[node] = r0 + excl;
        norm[node] = rsqrtf((float)(v > 1 ? v : 1));
    }
    if (rg == NR - 1 && t == 0) offsets[N] = E;
    __syncthreads();
    cnt[t] = r0 + excl;
    __syncthreads();
    for (int i = r0 + t; i < r1; i += RB) {
        unsigned int u = ebuf2[i];
        int pos = atomicAdd(&cnt[u >> 17], 1);
        csr[pos] = (int)(u & 0x1FFFFu);
    }
}

// ---- hop 0: g0 = f16(f*norm); if do_pool also out = sigmoid(f.s)*f ------

__global__ void hop0(const float4* __restrict__ feat, const float* __restrict__ s,
                     const float* __restrict__ norm, uint4* __restrict__ g0,
                     float4* __restrict__ out, int n, int do_pool) {
    int t = blockIdx.x * blockDim.x + threadIdx.x;
    int node = t >> 3;
    int l = t & 7;
    if (node > n) return;
    if (node == n) {                           // zero pad row
        g0[(size_t)n * 8 + l] = make_uint4(0u, 0u, 0u, 0u);
        return;
    }
    float4 f0 = feat[node * 16 + 2 * l];
    float4 f1 = feat[node * 16 + 2 * l + 1];
    float nv = norm[node];
    U4H P;
    P.h[0] = __floats2half2_rn(f0.x * nv, f0.y * nv);
    P.h[1] = __floats2half2_rn(f0.z * nv, f0.w * nv);
    P.h[2] = __floats2half2_rn(f1.x * nv, f1.y * nv);
    P.h[3] = __floats2half2_rn(f1.z * nv, f1.w * nv);
    g0[(size_t)node * 8 + l] = P.u;
    if (do_pool) {
        const float4* s4 = (const float4*)s;
        float4 a = s4[2 * l], b = s4[2 * l + 1];
        float dot = f0.x * a.x + f0.y * a.y + f0.z * a.z + f0.w * a.w
                  + f1.x * b.x + f1.y * b.y + f1.z * b.z + f1.w * b.w;
        #pragma unroll
        for (int m = 1; m <= 4; m <<= 1) dot += __shfl_xor(dot, m, 64);
        float sig = 1.0f / (1.0f + expf(-dot));
        out[node * 16 + 2 * l]     = make_float4(sig * f0.x, sig * f0.y, sig * f0.z, sig * f0.w);
        out[node * 16 + 2 * l + 1] = make_float4(sig * f1.x, sig * f1.y, sig * f1.z, sig * f1.w);
    }
}

// ---- hop t: persistent gather-SpMM with depth-2 software pipeline -------
// Grid-stride: wave wid handles nodes wid, wid+W, ... Steady state per
// iteration: gathers for node i are in flight; at iter top we shuffle the
// already-landed csr indices of node i+1, issue its 4 gathers PLUS node
// i+2's csr index load (5 loads in flight), sched_barrier(0), then consume
// node i (accumulate/butterfly/store) while they fly. Double-buffered
// gather regs via 2x-unrolled body (static names only). Numerics are
// bit-identical to the single-node version: unconditional gathers, invalid
// slots hit the all-zero pad row n (exact +0 in f16).

#define CONSUME(C0, C1, C2, C3)                                               \
    {                                                                         \
        __half2 ah0, ah1, ah2, ah3;                                           \
        ah0 = __hadd2(C0.h[0], C1.h[0]); ah1 = __hadd2(C0.h[1], C1.h[1]);     \
        ah2 = __hadd2(C0.h[2], C1.h[2]); ah3 = __hadd2(C0.h[3], C1.h[3]);     \
        ah0 = __hadd2(ah0, C2.h[0]);     ah1 = __hadd2(ah1, C2.h[1]);         \
        ah2 = __hadd2(ah2, C2.h[2]);     ah3 = __hadd2(ah3, C2.h[3]);         \
        ah0 = __hadd2(ah0, C3.h[0]);     ah1 = __hadd2(ah1, C3.h[1]);         \
        ah2 = __hadd2(ah2, C3.h[2]);     ah3 = __hadd2(ah3, C3.h[3]);         \
        float2 q0 = __half22float2(ah0), q1 = __half22float2(ah1);            \
        float2 q2 = __half22float2(ah2), q3 = __half22float2(ah3);            \
        float acc[8] = {q0.x, q0.y, q1.x, q1.y, q2.x, q2.y, q3.x, q3.y};      \
        for (int i = begC + 32 + g; i < endC; i += 8) {                       \
            U4H P; P.u = gin[(size_t)csr[i] * 8 + l];                         \
            float2 a0 = __half22float2(P.h[0]), a1 = __half22float2(P.h[1]);  \
            float2 a2 = __half22float2(P.h[2]), a3 = __half22float2(P.h[3]);  \
            acc[0] += a0.x; acc[1] += a0.y; acc[2] += a1.x; acc[3] += a1.y;   \
            acc[4] += a2.x; acc[5] += a2.y; acc[6] += a3.x; acc[7] += a3.y;   \
        }                                                                     \
        _Pragma("unroll")                                                     \
        for (int m = 8; m <= 32; m <<= 1) {                                   \
            _Pragma("unroll")                                                 \
            for (int jj = 0; jj < 8; ++jj) acc[jj] += __shfl_xor(acc[jj], m, 64); \
        }                                                                     \
        float nv = norm[cur];                                                 \
        float h0 = acc[0] * nv, h1 = acc[1] * nv, h2 = acc[2] * nv, h3 = acc[3] * nv; \
        float h4 = acc[4] * nv, h5 = acc[5] * nv, h6 = acc[6] * nv, h7 = acc[7] * nv; \
        float sig = 0.f;                                                      \
        if (do_pool) {                                                        \
            float dot = h0 * sa.x + h1 * sa.y + h2 * sa.z + h3 * sa.w         \
                      + h4 * sb.x + h5 * sb.y + h6 * sb.z + h7 * sb.w;        \
            _Pragma("unroll")                                                 \
            for (int m = 1; m <= 4; m <<= 1) dot += __shfl_xor(dot, m, 64);   \
            sig = 1.0f / (1.0f + expf(-dot));                                 \
        }                                                                     \
        if (g == 0) {                                                         \
            if (write_g) {                                                    \
                U4H P;                                                        \
                P.h[0] = __floats2half2_rn(h0 * nv, h1 * nv);                 \
                P.h[1] = __floats2half2_rn(h2 * nv, h3 * nv);                 \
                P.h[2] = __floats2half2_rn(h4 * nv, h5 * nv);                 \
                P.h[3] = __floats2half2_rn(h6 * nv, h7 * nv);                 \
                gout[(size_t)cur * 8 + l] = P.u;                              \
            }                                                                 \
            if (do_pool) {                                                    \
                float4 o0 = out[cur * 16 + 2 * l];                            \
                float4 o1 = out[cur * 16 + 2 * l + 1];                        \
                o0.x += sig * h0; o0.y += sig * h1; o0.z += sig * h2; o0.w += sig * h3; \
                o1.x += sig * h4; o1.y += sig * h5; o1.z += sig * h6; o1.w += sig * h7; \
                out[cur * 16 + 2 * l]     = o0;                               \
                out[cur * 16 + 2 * l + 1] = o1;                               \
            }                                                                 \
        }                                                                     \
    }

#define BODY(IA0, IA1, IA2, IA3, IB0, IB1, IB2, IB3)                          \
    {                                                                         \
        int u0 = __shfl(idxN, g,      64);                                    \
        int u1 = __shfl(idxN, g + 8,  64);                                    \
        int u2 = __shfl(idxN, g + 16, 64);                                    \
        int u3 = __shfl(idxN, g + 24, 64);                                    \
        IB0.u = gin[(size_t)u0 * 8 + l];                                      \
        IB1.u = gin[(size_t)u1 * 8 + l];                                      \
        IB2.u = gin[(size_t)u2 * 8 + l];                                      \
        IB3.u = gin[(size_t)u3 * 8 + l];                                      \
        int nxt2 = nxt + W;                                                   \
        int vn2 = (nxt2 < n);                                                 \
        int bN2 = 0, eN2 = 0;                                                 \
        if (vn2) { bN2 = offsets[nxt2]; eN2 = offsets[nxt2 + 1]; }            \
        int dc2 = eN2 - bN2; if (dc2 > 32) dc2 = 32;                          \
        int idx2 = (vn2 && lane < dc2) ? csr[bN2 + lane] : n;                 \
        __builtin_amdgcn_sched_barrier(0);                                    \
        CONSUME(IA0, IA1, IA2, IA3)                                           \
        if (!vn) break;                                                       \
        cur = nxt; begC = bN; endC = eN;                                      \
        nxt = nxt2; vn = vn2; bN = bN2; eN = eN2; idxN = idx2;                \
    }

__global__ __launch_bounds__(256, 4)
void spmm_hop(const uint4* __restrict__ gin, const int* __restrict__ offsets,
              const int* __restrict__ csr, const float* __restrict__ norm,
              const float* __restrict__ s, uint4* __restrict__ gout,
              float4* __restrict__ out, int n, int do_pool, int write_g) {
    int lane = threadIdx.x & 63;
    int g = lane >> 3;
    int l = lane & 7;
    int wid = __builtin_amdgcn_readfirstlane((int)blockIdx.x * 4 + (threadIdx.x >> 6));
    int W = (int)gridDim.x * 4;

    if (write_g && wid == 0 && g == 0)       // maintain zero pad row in gout
        gout[(size_t)n * 8 + l] = make_uint4(0u, 0u, 0u, 0u);

    float4 sa = make_float4(0.f, 0.f, 0.f, 0.f), sb = sa;
    if (do_pool) {
        const float4* s4 = (const float4*)s;
        sa = s4[2 * l]; sb = s4[2 * l + 1];
    }

    int cur = wid;
    if (cur >= n) return;                    // wave-uniform

    // ---- prolog: node cur's csr + gathers; node nxt's csr ----
    int begC = offsets[cur], endC = offsets[cur + 1];
    int dcC = endC - begC; if (dcC > 32) dcC = 32;
    int idxC = (lane < dcC) ? csr[begC + lane] : n;

    int nxt = cur + W;
    int vn = (nxt < n);
    int bN = 0, eN = 0;
    if (vn) { bN = offsets[nxt]; eN = offsets[nxt + 1]; }
    int dcN = eN - bN; if (dcN > 32) dcN = 32;

    U4H A0, A1, A2, A3, B0, B1, B2, B3;
    {
        int u0 = __shfl(idxC, g,      64);
        int u1 = __shfl(idxC, g + 8,  64);
        int u2 = __shfl(idxC, g + 16, 64);
        int u3 = __shfl(idxC, g + 24, 64);
        A0.u = gin[(size_t)u0 * 8 + l];
        A1.u = gin[(size_t)u1 * 8 + l];
        A2.u = gin[(size_t)u2 * 8 + l];
        A3.u = gin[(size_t)u3 * 8 + l];
    }
    int idxN = (vn && lane < dcN) ? csr[bN + lane] : n;

    // ---- steady state: 2x-unrolled pipeline (A consumes, B fills; swap) --
    for (;;) {
        BODY(A0, A1, A2, A3, B0, B1, B2, B3)
        BODY(B0, B1, B2, B3, A0, A1, A2, A3)
    }
}

// ---- deferred pooling epilogue ------------------------------------------
// out = sum_t sigmoid((g_t . s)/nv) * g_t / nv   over t=0..KHOPS

__global__ void pool_epilogue(const uint4* __restrict__ gbase, size_t gstride,
                              const float* __restrict__ norm,
                              const float* __restrict__ s,
                              float4* __restrict__ out, int N) {
    int t0 = blockIdx.x * blockDim.x + threadIdx.x;
    int node = t0 >> 3;
    int l = t0 & 7;
    if (node >= N) return;          // uniform per 8-lane group
    float inv_nv = 1.0f / norm[node];
    const float4* s4 = (const float4*)s;
    float4 sa = s4[2 * l], sb = s4[2 * l + 1];
    float o[8] = {0.f, 0.f, 0.f, 0.f, 0.f, 0.f, 0.f, 0.f};
    for (int t = 0; t <= KHOPS; ++t) {
        U4H P; P.u = gbase[(size_t)t * gstride + (size_t)node * 8 + l];
        float2 a0 = __half22float2(P.h[0]), a1 = __half22float2(P.h[1]);
        float2 a2 = __half22float2(P.h[2]), a3 = __half22float2(P.h[3]);
        float gf[8] = {a0.x, a0.y, a1.x, a1.y, a2.x, a2.y, a3.x, a3.y};
        float dot = gf[0] * sa.x + gf[1] * sa.y + gf[2] * sa.z + gf[3] * sa.w
                  + gf[4] * sb.x + gf[5] * sb.y + gf[6] * sb.z + gf[7] * sb.w;
        #pragma unroll
        for (int m = 1; m <= 4; m <<= 1) dot += __shfl_xor(dot, m, 64);
        float sig = 1.0f / (1.0f + expf(-dot * inv_nv));
        float sc = sig * inv_nv;
        #pragma unroll
        for (int j = 0; j < 8; ++j) o[j] += sc * gf[j];
    }
    out[node * 16 + 2 * l]     = make_float4(o[0], o[1], o[2], o[3]);
    out[node * 16 + 2 * l + 1] = make_float4(o[4], o[5], o[6], o[7]);
}

// ---- launcher -----------------------------------------------------------

extern "C" void kernel_launch(void* const* d_in, const int* in_sizes, int n_in,
                              void* d_out, int out_size, void* d_ws, size_t ws_size,
                              hipStream_t stream) {
    const float* feat = (const float*)d_in[0];
    const float* s    = (const float*)d_in[1];
    const int*   src  = (const int*)d_in[2];
    const int*   dst  = (const int*)d_in[3];

    int N = in_sizes[0] / D;
    int E = in_sizes[2];
    int NR   = (N + RB - 1) / RB;          // 98 ranges  (<= NRMAX)
    int NBLK = (E + EB - 1) / EB;          // 782 edge blocks
    int M    = NR * NBLK;
    int nchA = (M + 1023) / 1024;

    // fixed workspace layout
    int*   offsets  = (int*)d_ws;                  // N+1
    int*   csr      = offsets + (N + 1);           // E
    float* norm     = (float*)(csr + E);           // N
    int*   countsA  = (int*)(norm + N);            // M
    int*   baseA    = countsA + M;                 // M
    int*   bsumA    = baseA + M;                   // nchA
    uintptr_t p = (uintptr_t)(bsumA + nchA);
    p = (p + 255) & ~(uintptr_t)255;
    uint4* gbase = (uint4*)p;                      // f16 rows: (N+1)*8 uint4/buffer
    size_t gstride = (size_t)(N + 1) * 8;          // uint4 per buffer (row N = zeros)

    // deferred pooling needs KHOPS+1 g buffers; fall back to 2-buffer ping-pong
    size_t fixed_bytes = (uintptr_t)gbase - (uintptr_t)d_ws;
    int deferred = (ws_size >= fixed_bytes + (size_t)(KHOPS + 1) * gstride * sizeof(uint4)) ? 1 : 0;

    // ebuf2 (E u32 = 6.4MB) aliases g buffer #1 (first written by the first
    // spmm hop, after range_build has consumed ebuf2)
    unsigned int* ebuf2 = (unsigned int*)(gbase + gstride);

    // multisplit CSR build (zero global atomics)
    countA<<<NBLK, 256, 0, stream>>>(dst, countsA, E, NR, NBLK);
    block_sums<<<nchA, 256, 0, stream>>>(countsA, bsumA, M);
    scan_bsums<<<1, 1024, 0, stream>>>(bsumA, nchA);
    gen_scan2<<<nchA, 1024, 0, stream>>>(countsA, bsumA, baseA, M);
    passA2<<<NBLK, 256, 0, stream>>>(src, dst, baseA, ebuf2, E, NR, NBLK);
    range_build<<<NR, RB, 0, stream>>>(ebuf2, baseA, offsets, norm, csr, N, E, NR, NBLK);

    float4* outp = (float4*)d_out;
    int nb_node8 = ((N + 1) * 8 + 255) / 256;      // MUST cover pad node N
    int nb_spmm  = SPMM_BLOCKS;                    // persistent grid-stride

    hop0<<<nb_node8, 256, 0, stream>>>((const float4*)feat, s, norm, gbase,
                                       outp, N, deferred ? 0 : 1);

    if (deferred) {
        for (int t = 0; t < KHOPS; ++t) {
            spmm_hop<<<nb_spmm, 256, 0, stream>>>(
                gbase + (size_t)t * gstride, offsets, csr, norm, s,
                gbase + (size_t)(t + 1) * gstride, outp, N, 0, 1);
        }
        pool_epilogue<<<nb_node8, 256, 0, stream>>>(gbase, gstride, norm, s, outp, N);
    } else {
        uint4* gin = gbase;
        uint4* gout = gbase + gstride;
        for (int t = 0; t < KHOPS; ++t) {
            spmm_hop<<<nb_spmm, 256, 0, stream>>>(
                gin, offsets, csr, norm, s, gout, outp, N, 1, (t < KHOPS - 1) ? 1 : 0);
            uint4* tmp = gin; gin = gout; gout = tmp;
        }
    }
}

// Round 6
// 536.304 us; speedup vs baseline: 1.0950x; 1.0950x over previous
//
#include <hip/hip_runtime.h>
#include <hip/hip_fp16.h>
#include <math.h>

#define D 64
#define RB 1024          // nodes per range (must match >>10 / &1023 below)
#define EB 2048          // edges per partition block
#define NRMAX 128        // static LDS sizing; NR = ceil(N/RB) must be <= NRMAX
#define KHOPS 10
#define SPMM_BLOCKS 2048 // persistent spmm grid: exactly 8 blocks/CU on 256 CUs

// ---- helpers ------------------------------------------------------------

typedef union { uint4 u; __half2 h[4]; } U4H;

// ---- multisplit CSR build (no global atomics anywhere) ------------------

__global__ void countA(const int* __restrict__ dst, int* __restrict__ countsA_T,
                       int E, int NR, int NBLK) {
    __shared__ int hist[NRMAX];
    int t = threadIdx.x;
    for (int i = t; i < NR; i += 256) hist[i] = 0;
    __syncthreads();
    int base = blockIdx.x * EB + t;
    #pragma unroll
    for (int j = 0; j < EB / 256; ++j) {
        int e = base + j * 256;
        if (e < E) atomicAdd(&hist[dst[e] >> 10], 1);
    }
    __syncthreads();
    for (int i = t; i < NR; i += 256) countsA_T[i * NBLK + blockIdx.x] = hist[i];
}

__global__ void block_sums(const int* __restrict__ arr, int* __restrict__ bsum, int n) {
    int base = blockIdx.x * 1024;
    int t = threadIdx.x;
    int v = 0;
    #pragma unroll
    for (int j = 0; j < 4; ++j) {
        int i = base + t + j * 256;
        if (i < n) v += arr[i];
    }
    #pragma unroll
    for (int m = 32; m >= 1; m >>= 1) v += __shfl_xor(v, m, 64);
    __shared__ int ws[4];
    if ((t & 63) == 0) ws[t >> 6] = v;
    __syncthreads();
    if (t == 0) bsum[blockIdx.x] = ws[0] + ws[1] + ws[2] + ws[3];
}

__global__ void scan_bsums(int* __restrict__ bsum, int nb) {
    __shared__ int tmp[1024];
    int t = threadIdx.x;
    int v = (t < nb) ? bsum[t] : 0;
    tmp[t] = v;
    __syncthreads();
    for (int off = 1; off < 1024; off <<= 1) {
        int x = (t >= off) ? tmp[t - off] : 0;
        __syncthreads();
        tmp[t] += x;
        __syncthreads();
    }
    if (t < nb) bsum[t] = tmp[t] - v;
}

__global__ void gen_scan2(const int* __restrict__ arr, const int* __restrict__ bsum,
                          int* __restrict__ out, int n) {
    __shared__ int tmp[1024];
    int base = blockIdx.x * 1024;
    int t = threadIdx.x;
    int i = base + t;
    int v = (i < n) ? arr[i] : 0;
    tmp[t] = v;
    __syncthreads();
    for (int off = 1; off < 1024; off <<= 1) {
        int x = (t >= off) ? tmp[t - off] : 0;
        __syncthreads();
        tmp[t] += x;
        __syncthreads();
    }
    if (i < n) out[i] = bsum[blockIdx.x] + tmp[t] - v;
}

__global__ void passA2(const int* __restrict__ src, const int* __restrict__ dst,
                       const int* __restrict__ baseA, unsigned int* __restrict__ ebuf2,
                       int E, int NR, int NBLK) {
    __shared__ int cur[NRMAX];
    int t = threadIdx.x;
    for (int i = t; i < NR; i += 256) cur[i] = baseA[i * NBLK + blockIdx.x];
    __syncthreads();
    int base = blockIdx.x * EB + t;
    #pragma unroll
    for (int j = 0; j < EB / 256; ++j) {
        int e = base + j * 256;
        if (e < E) {
            int v = dst[e];
            int pos = atomicAdd(&cur[v >> 10], 1);
            ebuf2[pos] = (unsigned int)src[e] | ((unsigned int)(v & (RB - 1)) << 17);
        }
    }
}

__global__ void range_build(const unsigned int* __restrict__ ebuf2,
                            const int* __restrict__ baseA,
                            int* __restrict__ offsets, float* __restrict__ norm,
                            int* __restrict__ csr, int N, int E, int NR, int NBLK) {
    __shared__ int cnt[RB];
    __shared__ int sc[RB];
    int rg = blockIdx.x;
    int t = threadIdx.x;
    int r0 = baseA[rg * NBLK];
    int r1 = (rg + 1 < NR) ? baseA[(rg + 1) * NBLK] : E;
    cnt[t] = 0;
    __syncthreads();
    for (int i = r0 + t; i < r1; i += RB)
        atomicAdd(&cnt[ebuf2[i] >> 17], 1);
    __syncthreads();
    int v = cnt[t];
    sc[t] = v;
    __syncthreads();
    for (int off = 1; off < RB; off <<= 1) {
        int x = (t >= off) ? sc[t - off] : 0;
        __syncthreads();
        sc[t] += x;
        __syncthreads();
    }
    int excl = sc[t] - v;
    int node = rg * RB + t;
    if (node < N) {
        offsets[node] = r0 + excl;
        norm[node] = rsqrtf((float)(v > 1 ? v : 1));
    }
    if (rg == NR - 1 && t == 0) offsets[N] = E;
    __syncthreads();
    cnt[t] = r0 + excl;
    __syncthreads();
    for (int i = r0 + t; i < r1; i += RB) {
        unsigned int u = ebuf2[i];
        int pos = atomicAdd(&cnt[u >> 17], 1);
        csr[pos] = (int)(u & 0x1FFFFu);
    }
}

// ---- hop 0: g0 = f16(f*norm); if do_pool also out = sigmoid(f.s)*f ------

__global__ void hop0(const float4* __restrict__ feat, const float* __restrict__ s,
                     const float* __restrict__ norm, uint4* __restrict__ g0,
                     float4* __restrict__ out, int n, int do_pool) {
    int t = blockIdx.x * blockDim.x + threadIdx.x;
    int node = t >> 3;
    int l = t & 7;
    if (node > n) return;
    if (node == n) {                           // zero pad row
        g0[(size_t)n * 8 + l] = make_uint4(0u, 0u, 0u, 0u);
        return;
    }
    float4 f0 = feat[node * 16 + 2 * l];
    float4 f1 = feat[node * 16 + 2 * l + 1];
    float nv = norm[node];
    U4H P;
    P.h[0] = __floats2half2_rn(f0.x * nv, f0.y * nv);
    P.h[1] = __floats2half2_rn(f0.z * nv, f0.w * nv);
    P.h[2] = __floats2half2_rn(f1.x * nv, f1.y * nv);
    P.h[3] = __floats2half2_rn(f1.z * nv, f1.w * nv);
    g0[(size_t)node * 8 + l] = P.u;
    if (do_pool) {
        const float4* s4 = (const float4*)s;
        float4 a = s4[2 * l], b = s4[2 * l + 1];
        float dot = f0.x * a.x + f0.y * a.y + f0.z * a.z + f0.w * a.w
                  + f1.x * b.x + f1.y * b.y + f1.z * b.z + f1.w * b.w;
        #pragma unroll
        for (int m = 1; m <= 4; m <<= 1) dot += __shfl_xor(dot, m, 64);
        float sig = 1.0f / (1.0f + expf(-dot));
        out[node * 16 + 2 * l]     = make_float4(sig * f0.x, sig * f0.y, sig * f0.z, sig * f0.w);
        out[node * 16 + 2 * l + 1] = make_float4(sig * f1.x, sig * f1.y, sig * f1.z, sig * f1.w);
    }
}

// ---- hop t: PERSISTENT gather-SpMM, R4's proven single-node body --------
// Evidence across R2-R5: dur tracks 1/occupancy; per-wave ILP moves <=10%.
// The 25k short-lived blocks were starving occupancy at ~66% (workgroup
// refill limit). Fix: 2048 persistent blocks (exactly 8/CU = 32 waves/CU
// resident for the whole hop), each wave grid-strides over ~12 nodes with
// the codegen-verified R4 body (4 unconditional gathers + sched_barrier,
// VGPR 40). Minimal 1-deep lookahead: while node i's gathers fly, issue
// node i+1's csr-index load and node i+2's offsets s_load (independent,
// same latency class). NO double-buffered gather regs (the compiler
// refuses to keep them live - R3/R5 evidence). Numerics bit-identical:
// unconditional gathers, invalid slots hit the all-zero pad row n.

__global__ __launch_bounds__(256, 8)
void spmm_hop(const uint4* __restrict__ gin, const int* __restrict__ offsets,
              const int* __restrict__ csr, const float* __restrict__ norm,
              const float* __restrict__ s, uint4* __restrict__ gout,
              float4* __restrict__ out, int n, int do_pool, int write_g) {
    int lane = threadIdx.x & 63;
    int g = lane >> 3;
    int l = lane & 7;
    int wid = __builtin_amdgcn_readfirstlane((int)blockIdx.x * 4 + (threadIdx.x >> 6));
    int W = (int)gridDim.x * 4;

    if (write_g && wid == 0 && g == 0)       // maintain zero pad row in gout
        gout[(size_t)n * 8 + l] = make_uint4(0u, 0u, 0u, 0u);

    float4 sa = make_float4(0.f, 0.f, 0.f, 0.f), sb = sa;
    if (do_pool) {
        const float4* s4 = (const float4*)s;
        sa = s4[2 * l]; sb = s4[2 * l + 1];
    }

    int cur = wid;
    if (cur >= n) return;                    // wave-uniform

    // prolog: node cur's offsets + csr indices; node nxt's offsets
    int beg = offsets[cur], end = offsets[cur + 1];
    int dc = end - beg; if (dc > 32) dc = 32;
    int idx = (lane < dc) ? csr[beg + lane] : n;

    int nxt = cur + W;
    int vn = (nxt < n);
    int b1 = 0, e1 = 0;
    if (vn) { b1 = offsets[nxt]; e1 = offsets[nxt + 1]; }

    for (;;) {
        // ---- issue phase (all independent loads, then barrier) ----
        int u0 = __shfl(idx, g,      64);
        int u1 = __shfl(idx, g + 8,  64);
        int u2 = __shfl(idx, g + 16, 64);
        int u3 = __shfl(idx, g + 24, 64);
        U4H A0, A1, A2, A3;
        A0.u = gin[(size_t)u0 * 8 + l];
        A1.u = gin[(size_t)u1 * 8 + l];
        A2.u = gin[(size_t)u2 * 8 + l];
        A3.u = gin[(size_t)u3 * 8 + l];
        // next node's csr indices (uses b1/e1 loaded last iteration)
        int dc1 = e1 - b1; if (dc1 > 32) dc1 = 32;
        int idx2 = (vn && lane < dc1) ? csr[b1 + lane] : n;
        // next-next node's offsets (scalar loads, consumed next iteration)
        int nxt2 = nxt + W;
        int vn2 = (nxt2 < n);
        int b2 = 0, e2 = 0;
        if (vn2) { b2 = offsets[nxt2]; e2 = offsets[nxt2 + 1]; }
        __builtin_amdgcn_sched_barrier(0);   // loads above; consume below

        // ---- consume phase (identical math to prior rounds) ----
        __half2 ah0, ah1, ah2, ah3;
        ah0 = __hadd2(A0.h[0], A1.h[0]); ah1 = __hadd2(A0.h[1], A1.h[1]);
        ah2 = __hadd2(A0.h[2], A1.h[2]); ah3 = __hadd2(A0.h[3], A1.h[3]);
        ah0 = __hadd2(ah0, A2.h[0]);     ah1 = __hadd2(ah1, A2.h[1]);
        ah2 = __hadd2(ah2, A2.h[2]);     ah3 = __hadd2(ah3, A2.h[3]);
        ah0 = __hadd2(ah0, A3.h[0]);     ah1 = __hadd2(ah1, A3.h[1]);
        ah2 = __hadd2(ah2, A3.h[2]);     ah3 = __hadd2(ah3, A3.h[3]);

        float2 q0 = __half22float2(ah0), q1 = __half22float2(ah1);
        float2 q2 = __half22float2(ah2), q3 = __half22float2(ah3);
        float acc[8] = {q0.x, q0.y, q1.x, q1.y, q2.x, q2.y, q3.x, q3.y};

        for (int i = beg + 32 + g; i < end; i += 8) {   // deg>32: rare
            U4H P; P.u = gin[(size_t)csr[i] * 8 + l];
            float2 a0 = __half22float2(P.h[0]), a1 = __half22float2(P.h[1]);
            float2 a2 = __half22float2(P.h[2]), a3 = __half22float2(P.h[3]);
            acc[0] += a0.x; acc[1] += a0.y; acc[2] += a1.x; acc[3] += a1.y;
            acc[4] += a2.x; acc[5] += a2.y; acc[6] += a3.x; acc[7] += a3.y;
        }

        #pragma unroll
        for (int m = 8; m <= 32; m <<= 1) {
            #pragma unroll
            for (int jj = 0; jj < 8; ++jj) acc[jj] += __shfl_xor(acc[jj], m, 64);
        }

        float nv = norm[cur];
        float h0 = acc[0] * nv, h1 = acc[1] * nv, h2 = acc[2] * nv, h3 = acc[3] * nv;
        float h4 = acc[4] * nv, h5 = acc[5] * nv, h6 = acc[6] * nv, h7 = acc[7] * nv;

        float sig = 0.f;
        if (do_pool) {                   // wave-uniform flag
            float dot = h0 * sa.x + h1 * sa.y + h2 * sa.z + h3 * sa.w
                      + h4 * sb.x + h5 * sb.y + h6 * sb.z + h7 * sb.w;
            #pragma unroll
            for (int m = 1; m <= 4; m <<= 1) dot += __shfl_xor(dot, m, 64);
            sig = 1.0f / (1.0f + expf(-dot));
        }

        if (g == 0) {
            if (write_g) {
                U4H P;
                P.h[0] = __floats2half2_rn(h0 * nv, h1 * nv);
                P.h[1] = __floats2half2_rn(h2 * nv, h3 * nv);
                P.h[2] = __floats2half2_rn(h4 * nv, h5 * nv);
                P.h[3] = __floats2half2_rn(h6 * nv, h7 * nv);
                gout[(size_t)cur * 8 + l] = P.u;
            }
            if (do_pool) {
                float4 o0 = out[cur * 16 + 2 * l];
                float4 o1 = out[cur * 16 + 2 * l + 1];
                o0.x += sig * h0; o0.y += sig * h1; o0.z += sig * h2; o0.w += sig * h3;
                o1.x += sig * h4; o1.y += sig * h5; o1.z += sig * h6; o1.w += sig * h7;
                out[cur * 16 + 2 * l]     = o0;
                out[cur * 16 + 2 * l + 1] = o1;
            }
        }

        if (!vn) break;
        cur = nxt; beg = b1; end = e1; idx = idx2;
        nxt = nxt2; vn = vn2; b1 = b2; e1 = e2;
    }
}

// ---- deferred pooling epilogue ------------------------------------------
// out = sum_t sigmoid((g_t . s)/nv) * g_t / nv   over t=0..KHOPS

__global__ void pool_epilogue(const uint4* __restrict__ gbase, size_t gstride,
                              const float* __restrict__ norm,
                              const float* __restrict__ s,
                              float4* __restrict__ out, int N) {
    int t0 = blockIdx.x * blockDim.x + threadIdx.x;
    int node = t0 >> 3;
    int l = t0 & 7;
    if (node >= N) return;          // uniform per 8-lane group
    float inv_nv = 1.0f / norm[node];
    const float4* s4 = (const float4*)s;
    float4 sa = s4[2 * l], sb = s4[2 * l + 1];
    float o[8] = {0.f, 0.f, 0.f, 0.f, 0.f, 0.f, 0.f, 0.f};
    for (int t = 0; t <= KHOPS; ++t) {
        U4H P; P.u = gbase[(size_t)t * gstride + (size_t)node * 8 + l];
        float2 a0 = __half22float2(P.h[0]), a1 = __half22float2(P.h[1]);
        float2 a2 = __half22float2(P.h[2]), a3 = __half22float2(P.h[3]);
        float gf[8] = {a0.x, a0.y, a1.x, a1.y, a2.x, a2.y, a3.x, a3.y};
        float dot = gf[0] * sa.x + gf[1] * sa.y + gf[2] * sa.z + gf[3] * sa.w
                  + gf[4] * sb.x + gf[5] * sb.y + gf[6] * sb.z + gf[7] * sb.w;
        #pragma unroll
        for (int m = 1; m <= 4; m <<= 1) dot += __shfl_xor(dot, m, 64);
        float sig = 1.0f / (1.0f + expf(-dot * inv_nv));
        float sc = sig * inv_nv;
        #pragma unroll
        for (int j = 0; j < 8; ++j) o[j] += sc * gf[j];
    }
    out[node * 16 + 2 * l]     = make_float4(o[0], o[1], o[2], o[3]);
    out[node * 16 + 2 * l + 1] = make_float4(o[4], o[5], o[6], o[7]);
}

// ---- launcher -----------------------------------------------------------

extern "C" void kernel_launch(void* const* d_in, const int* in_sizes, int n_in,
                              void* d_out, int out_size, void* d_ws, size_t ws_size,
                              hipStream_t stream) {
    const float* feat = (const float*)d_in[0];
    const float* s    = (const float*)d_in[1];
    const int*   src  = (const int*)d_in[2];
    const int*   dst  = (const int*)d_in[3];

    int N = in_sizes[0] / D;
    int E = in_sizes[2];
    int NR   = (N + RB - 1) / RB;          // 98 ranges  (<= NRMAX)
    int NBLK = (E + EB - 1) / EB;          // 782 edge blocks
    int M    = NR * NBLK;
    int nchA = (M + 1023) / 1024;

    // fixed workspace layout
    int*   offsets  = (int*)d_ws;                  // N+1
    int*   csr      = offsets + (N + 1);           // E
    float* norm     = (float*)(csr + E);           // N
    int*   countsA  = (int*)(norm + N);            // M
    int*   baseA    = countsA + M;                 // M
    int*   bsumA    = baseA + M;                   // nchA
    uintptr_t p = (uintptr_t)(bsumA + nchA);
    p = (p + 255) & ~(uintptr_t)255;
    uint4* gbase = (uint4*)p;                      // f16 rows: (N+1)*8 uint4/buffer
    size_t gstride = (size_t)(N + 1) * 8;          // uint4 per buffer (row N = zeros)

    // deferred pooling needs KHOPS+1 g buffers; fall back to 2-buffer ping-pong
    size_t fixed_bytes = (uintptr_t)gbase - (uintptr_t)d_ws;
    int deferred = (ws_size >= fixed_bytes + (size_t)(KHOPS + 1) * gstride * sizeof(uint4)) ? 1 : 0;

    // ebuf2 (E u32 = 6.4MB) aliases g buffer #1 (first written by the first
    // spmm hop, after range_build has consumed ebuf2)
    unsigned int* ebuf2 = (unsigned int*)(gbase + gstride);

    // multisplit CSR build (zero global atomics)
    countA<<<NBLK, 256, 0, stream>>>(dst, countsA, E, NR, NBLK);
    block_sums<<<nchA, 256, 0, stream>>>(countsA, bsumA, M);
    scan_bsums<<<1, 1024, 0, stream>>>(bsumA, nchA);
    gen_scan2<<<nchA, 1024, 0, stream>>>(countsA, bsumA, baseA, M);
    passA2<<<NBLK, 256, 0, stream>>>(src, dst, baseA, ebuf2, E, NR, NBLK);
    range_build<<<NR, RB, 0, stream>>>(ebuf2, baseA, offsets, norm, csr, N, E, NR, NBLK);

    float4* outp = (float4*)d_out;
    int nb_node8 = ((N + 1) * 8 + 255) / 256;      // MUST cover pad node N
    int nb_spmm  = SPMM_BLOCKS;                    // persistent: 8 blocks/CU

    hop0<<<nb_node8, 256, 0, stream>>>((const float4*)feat, s, norm, gbase,
                                       outp, N, deferred ? 0 : 1);

    if (deferred) {
        for (int t = 0; t < KHOPS; ++t) {
            spmm_hop<<<nb_spmm, 256, 0, stream>>>(
                gbase + (size_t)t * gstride, offsets, csr, norm, s,
                gbase + (size_t)(t + 1) * gstride, outp, N, 0, 1);
        }
        pool_epilogue<<<nb_node8, 256, 0, stream>>>(gbase, gstride, norm, s, outp, N);
    } else {
        uint4* gin = gbase;
        uint4* gout = gbase + gstride;
        for (int t = 0; t < KHOPS; ++t) {
            spmm_hop<<<nb_spmm, 256, 0, stream>>>(
                gin, offsets, csr, norm, s, gout, outp, N, 1, (t < KHOPS - 1) ? 1 : 0);
            uint4* tmp = gin; gin = gout; gout = tmp;
        }
    }
}